// Round 2
// baseline (236.287 us; speedup 1.0000x reference)
//
#include <hip/hip_runtime.h>
#include <hip/hip_bf16.h>
#include <stdint.h>

// Problem constants
#define NB   64          // batch*windows
#define NTOK 196         // tokens per window
#define NH   32          // heads
#define HD   4           // head dim
#define CE   128         // embed
#define NM   38416       // 196*196
#define ROWS 25088       // 2*64*196 (both branches stacked)

__device__ __forceinline__ float u2f(unsigned short u) {
    union { unsigned int i; float f; } z;
    z.i = ((unsigned int)u) << 16;
    return z.f;
}
__device__ __forceinline__ unsigned short f2u(float f) {
    union { float f; unsigned int i; } z; z.f = f;
    unsigned int x = z.i;
    return (unsigned short)((x + 0x7fffu + ((x >> 16) & 1u)) >> 16); // RNE
}

// ---------------------------------------------------------------------------
// Kernel 1: QKV GEMM.  rows = [branch, b, n] (25088), cols = 384 (jt picks q/k/v).
// Inputs fp32; staged to LDS as bf16 (tolerance is bf16-scale). 4x8 reg tile.
// ---------------------------------------------------------------------------
extern "C" __global__ __launch_bounds__(256) void qkv_gemm(
    const float* __restrict__ x1,
    const float* __restrict__ x2,
    const float* __restrict__ qkvw,
    float* __restrict__ Q, float* __restrict__ K, unsigned short* __restrict__ V)
{
    __shared__ unsigned short XT[128][72];   // [c][row], pad 72 for banks/align
    __shared__ unsigned short WT[128][136];  // [c][j],  pad 136
    const int tid = threadIdx.x;
    const int rt  = blockIdx.x;      // 0..391
    const int jt  = blockIdx.y;      // 0..2  -> q/k/v
    const int r0  = rt * 64;

    for (int idx = tid; idx < 64 * 128; idx += 256) {
        int rr = idx >> 7, c = idx & 127;
        int r = r0 + rr;
        const float* xp = (r >= 12544) ? x2 : x1;
        int rem = (r >= 12544) ? (r - 12544) : r;
        XT[c][rr] = f2u(xp[rem * 128 + c]);
    }
    for (int idx = tid; idx < 128 * 128; idx += 256) {
        int j = idx >> 7, c = idx & 127;
        WT[c][j] = f2u(qkvw[(jt * 128 + j) * 128 + c]);
    }
    __syncthreads();

    const int tx = tid & 15, ty = tid >> 4;   // j = tx*8.., r = ty*4..
    float acc[4][8];
#pragma unroll
    for (int i = 0; i < 4; ++i)
#pragma unroll
        for (int jj = 0; jj < 8; ++jj) acc[i][jj] = 0.f;

    for (int c = 0; c < 128; ++c) {
        ushort4 xu = *(const ushort4*)&XT[c][ty << 2];
        ushort4 w0 = *(const ushort4*)&WT[c][tx << 3];
        ushort4 w1 = *(const ushort4*)&WT[c][(tx << 3) + 4];
        float xs[4] = {u2f(xu.x), u2f(xu.y), u2f(xu.z), u2f(xu.w)};
        float ws[8] = {u2f(w0.x), u2f(w0.y), u2f(w0.z), u2f(w0.w),
                       u2f(w1.x), u2f(w1.y), u2f(w1.z), u2f(w1.w)};
#pragma unroll
        for (int i = 0; i < 4; ++i)
#pragma unroll
            for (int jj = 0; jj < 8; ++jj)
                acc[i][jj] = fmaf(xs[i], ws[jj], acc[i][jj]);
    }

#pragma unroll
    for (int i = 0; i < 4; ++i) {
        int r = r0 + (ty << 2) + i;
        int branch = (r >= 12544) ? 1 : 0;
        int rem = r - branch * 12544;
        int b = rem / 196;
        int n = rem - b * 196;
#pragma unroll
        for (int jj = 0; jj < 8; ++jj) {
            int j = (tx << 3) + jj;
            int h = j >> 2, dd = j & 3;
            float v = acc[i][jj];
            if (jt == 0) {
                Q[((branch * 64 + b) * 32 + h) * 784 + n * 4 + dd] = v * 0.5f;
            } else if (jt == 1) {
                K[((branch * 64 + b) * 32 + h) * 784 + n * 4 + dd] = v;
            } else {
                V[(b * 64 + branch * 32 + h) * 784 + n * 4 + dd] = f2u(v);
            }
        }
    }
}

// ---------------------------------------------------------------------------
// Kernel 2: relative-position-bias gather, stored TRANSPOSED: biasT[h][m*196+n]
// (so the attention kernel's per-m loads are coalesced over n = lane).
// ---------------------------------------------------------------------------
extern "C" __global__ __launch_bounds__(256) void bias_gather(
    const int* __restrict__ rel_idx, const float* __restrict__ rpb,
    unsigned short* __restrict__ biasT)
{
    int p = blockIdx.x * 256 + threadIdx.x;   // p = m*196 + n
    if (p >= NM) return;
    int m = p / 196;
    int n = p - m * 196;
    int idx = rel_idx[n * 196 + m];
    const float* row = rpb + idx * 32;
#pragma unroll
    for (int h = 0; h < 32; ++h)
        biasT[h * NM + p] = f2u(row[h]);
}

// ---------------------------------------------------------------------------
// Kernel 3: conv-gated value fusion + InstanceNorm + sigmoid(relu).
// Block = one (b, pair-of-o). 784 elems per o, 64-channel dot each.
// ---------------------------------------------------------------------------
__device__ __forceinline__ float block_sum(float v, float* red, int tid) {
#pragma unroll
    for (int off = 32; off > 0; off >>= 1) v += __shfl_down(v, off);
    __syncthreads();
    if ((tid & 63) == 0) red[tid >> 6] = v;
    __syncthreads();
    return red[0] + red[1] + red[2] + red[3];
}

__device__ __forceinline__ float act_sig_relu(float x) {
    return x > 0.f ? __fdividef(1.f, 1.f + __expf(-x)) : 0.5f;
}

extern "C" __global__ __launch_bounds__(256) void fuse_kernel(
    const unsigned short* __restrict__ V,
    const float* __restrict__ fuse_w,
    const float* __restrict__ fuse_b,
    float* __restrict__ Vf)
{
    const int b = blockIdx.x, o0 = blockIdx.y * 2;
    const int tid = threadIdx.x;
    __shared__ float fws[2][64];
    __shared__ float red[4];
    if (tid < 128) fws[tid >> 6][tid & 63] = fuse_w[(o0 + (tid >> 6)) * 64 + (tid & 63)];
    __syncthreads();

    const unsigned short* Vb = V + b * 64 * 784;
    float a0[3] = {0.f, 0.f, 0.f}, a1[3] = {0.f, 0.f, 0.f};
    float t0 = 0.f, t1 = 0.f;
    const bool tail = tid < 16;   // element tid+768 < 784
    for (int c = 0; c < 64; ++c) {
        float w0 = fws[0][c], w1 = fws[1][c];
        const unsigned short* Vc = Vb + c * 784;
#pragma unroll
        for (int k = 0; k < 3; ++k) {
            float x = u2f(Vc[tid + 256 * k]);
            a0[k] = fmaf(w0, x, a0[k]);
            a1[k] = fmaf(w1, x, a1[k]);
        }
        if (tail) {
            float x = u2f(Vc[tid + 768]);
            t0 = fmaf(w0, x, t0);
            t1 = fmaf(w1, x, t1);
        }
    }
    float fb0 = fuse_b[o0], fb1 = fuse_b[o0 + 1];
#pragma unroll
    for (int k = 0; k < 3; ++k) { a0[k] += fb0; a1[k] += fb1; }
    t0 += fb0; t1 += fb1;

    float s0 = a0[0] + a0[1] + a0[2] + (tail ? t0 : 0.f);
    float q0 = a0[0]*a0[0] + a0[1]*a0[1] + a0[2]*a0[2] + (tail ? t0*t0 : 0.f);
    float s1 = a1[0] + a1[1] + a1[2] + (tail ? t1 : 0.f);
    float q1 = a1[0]*a1[0] + a1[1]*a1[1] + a1[2]*a1[2] + (tail ? t1*t1 : 0.f);

    float S0 = block_sum(s0, red, tid);
    float Q0 = block_sum(q0, red, tid);
    float S1 = block_sum(s1, red, tid);
    float Q1 = block_sum(q1, red, tid);

    const float inv = 1.0f / 784.0f;
    float mu0 = S0 * inv, mu1 = S1 * inv;
    float rs0 = rsqrtf(Q0 * inv - mu0 * mu0 + 1e-5f);
    float rs1 = rsqrtf(Q1 * inv - mu1 * mu1 + 1e-5f);

    float* out0 = Vf + (b * 32 + o0) * 784;
    float* out1 = out0 + 784;
#pragma unroll
    for (int k = 0; k < 3; ++k) {
        int e = tid + 256 * k;
        out0[e] = act_sig_relu((a0[k] - mu0) * rs0);
        out1[e] = act_sig_relu((a1[k] - mu1) * rs1);
    }
    if (tail) {
        out0[tid + 768] = act_sig_relu((t0 - mu0) * rs0);
        out1[tid + 768] = act_sig_relu((t1 - mu1) * rs1);
    }
}

// ---------------------------------------------------------------------------
// Kernel 4: attention. Block = (b,h). Lane = query row. No max-subtraction
// (logits bounded ~0.5), no cross-lane reduces. K/V staged in LDS (broadcast).
// ---------------------------------------------------------------------------
extern "C" __global__ __launch_bounds__(256) void attn_kernel(
    const float* __restrict__ Q, const float* __restrict__ K,
    const float* __restrict__ Vf, const unsigned short* __restrict__ biasT,
    unsigned short* __restrict__ Ob)
{
    const int bh = blockIdx.x;
    const int b = bh >> 5, h = bh & 31;
    __shared__ float k1s[196][4];
    __shared__ float k2s[196][4];
    __shared__ float vfs[196][4];
    const int tid = threadIdx.x;
    const int base1 = (b * 32 + h) * 784;          // branch 0
    const int base2 = ((64 + b) * 32 + h) * 784;   // branch 1
    const int basev = (b * 32 + h) * 784;
    for (int idx = tid; idx < 784; idx += 256) {
        (&k1s[0][0])[idx] = K[base1 + idx];
        (&k2s[0][0])[idx] = K[base2 + idx];
        (&vfs[0][0])[idx] = Vf[basev + idx];
    }
    __syncthreads();

    const int n = tid;
    if (n < 196) {
        float4 q1 = *(const float4*)(Q + base1 + n * 4);
        float4 q2 = *(const float4*)(Q + base2 + n * 4);
        const unsigned short* bp = biasT + h * NM + n;   // stride 196 over m
        float S = 0.f, o0 = 0.f, o1 = 0.f, o2 = 0.f, o3 = 0.f;
        for (int m = 0; m < 196; ++m) {
            float4 k1 = *(const float4*)&k1s[m][0];
            float4 k2 = *(const float4*)&k2s[m][0];
            float s = u2f(bp[m * 196]);
            s = fmaf(q1.x, k1.x, fmaf(q1.y, k1.y, fmaf(q1.z, k1.z, fmaf(q1.w, k1.w, s))));
            s = fmaf(q2.x, k2.x, fmaf(q2.y, k2.y, fmaf(q2.z, k2.z, fmaf(q2.w, k2.w, s))));
            float p = __expf(s);
            S += p;
            float4 vv = *(const float4*)&vfs[m][0];
            o0 = fmaf(p, vv.x, o0); o1 = fmaf(p, vv.y, o1);
            o2 = fmaf(p, vv.z, o2); o3 = fmaf(p, vv.w, o3);
        }
        float invS = __fdividef(1.f, S);
        unsigned short* op = Ob + (b * 196 + n) * 128 + h * 4;
        op[0] = f2u(o0 * invS); op[1] = f2u(o1 * invS);
        op[2] = f2u(o2 * invS); op[3] = f2u(o3 * invS);
    }
}

// ---------------------------------------------------------------------------
// Kernel 5: output projection [12544x128] @ projW^T + b -> fp32 out.
// ---------------------------------------------------------------------------
extern "C" __global__ __launch_bounds__(256) void proj_kernel(
    const unsigned short* __restrict__ Ob, const float* __restrict__ projw,
    const float* __restrict__ projb, float* __restrict__ out)
{
    __shared__ unsigned short XT[128][72];
    __shared__ unsigned short WT[128][136];
    const int tid = threadIdx.x;
    const int r0 = blockIdx.x * 64;

    for (int idx = tid; idx < 64 * 128; idx += 256) {
        int rr = idx >> 7, c = idx & 127;
        XT[c][rr] = Ob[(r0 + rr) * 128 + c];
    }
    for (int idx = tid; idx < 128 * 128; idx += 256) {
        int j = idx >> 7, c = idx & 127;
        WT[c][j] = f2u(projw[j * 128 + c]);
    }
    __syncthreads();

    const int tx = tid & 15, ty = tid >> 4;
    float acc[4][8];
#pragma unroll
    for (int i = 0; i < 4; ++i)
#pragma unroll
        for (int jj = 0; jj < 8; ++jj) acc[i][jj] = 0.f;

    for (int c = 0; c < 128; ++c) {
        ushort4 xu = *(const ushort4*)&XT[c][ty << 2];
        ushort4 w0 = *(const ushort4*)&WT[c][tx << 3];
        ushort4 w1 = *(const ushort4*)&WT[c][(tx << 3) + 4];
        float xs[4] = {u2f(xu.x), u2f(xu.y), u2f(xu.z), u2f(xu.w)};
        float ws[8] = {u2f(w0.x), u2f(w0.y), u2f(w0.z), u2f(w0.w),
                       u2f(w1.x), u2f(w1.y), u2f(w1.z), u2f(w1.w)};
#pragma unroll
        for (int i = 0; i < 4; ++i)
#pragma unroll
            for (int jj = 0; jj < 8; ++jj)
                acc[i][jj] = fmaf(xs[i], ws[jj], acc[i][jj]);
    }

    float pb[8];
#pragma unroll
    for (int jj = 0; jj < 8; ++jj) pb[jj] = projb[(tx << 3) + jj];

#pragma unroll
    for (int i = 0; i < 4; ++i) {
        int r = r0 + (ty << 2) + i;
        float4 o0, o1;
        o0.x = acc[i][0] + pb[0]; o0.y = acc[i][1] + pb[1];
        o0.z = acc[i][2] + pb[2]; o0.w = acc[i][3] + pb[3];
        o1.x = acc[i][4] + pb[4]; o1.y = acc[i][5] + pb[5];
        o1.z = acc[i][6] + pb[6]; o1.w = acc[i][7] + pb[7];
        *(float4*)(out + r * 128 + (tx << 3))     = o0;
        *(float4*)(out + r * 128 + (tx << 3) + 4) = o1;
    }
}

// ---------------------------------------------------------------------------
extern "C" void kernel_launch(void* const* d_in, const int* in_sizes, int n_in,
                              void* d_out, int out_size, void* d_ws, size_t ws_size,
                              hipStream_t stream)
{
    const float* x1    = (const float*)d_in[0];
    const float* x2    = (const float*)d_in[1];
    const float* qkvw  = (const float*)d_in[2];
    const float* projw = (const float*)d_in[3];
    const float* projb = (const float*)d_in[4];
    const float* rpb   = (const float*)d_in[5];
    const float* fw    = (const float*)d_in[6];
    const float* fb    = (const float*)d_in[7];
    const int*   rel   = (const int*)d_in[8];
    float* out = (float*)d_out;

    char* w = (char*)d_ws;
    float* Q            = (float*)(w);                       // 12,845,056 B
    float* K            = (float*)(w + 12845056);            // 12,845,056 B
    unsigned short* V   = (unsigned short*)(w + 25690112);   //  6,422,528 B (bf16)
    float* Vf           = (float*)(w + 32112640);            //  6,422,528 B
    unsigned short* bT  = (unsigned short*)(w + 38535168);   //  2,458,624 B (bf16)
    unsigned short* Ob  = (unsigned short*)(w + 40993792);   //  3,211,264 B (bf16)
    // total 44,205,056 bytes of d_ws used

    qkv_gemm   <<<dim3(392, 3), dim3(256), 0, stream>>>(x1, x2, qkvw, Q, K, V);
    bias_gather<<<dim3(151),    dim3(256), 0, stream>>>(rel, rpb, bT);
    fuse_kernel<<<dim3(64, 16), dim3(256), 0, stream>>>(V, fw, fb, Vf);
    attn_kernel<<<dim3(2048),   dim3(256), 0, stream>>>(Q, K, Vf, bT, Ob);
    proj_kernel<<<dim3(196),    dim3(256), 0, stream>>>(Ob, projw, projb, out);
}

// Round 3
// 177.181 us; speedup vs baseline: 1.3336x; 1.3336x over previous
//
#include <hip/hip_runtime.h>
#include <hip/hip_bf16.h>
#include <stdint.h>

// Problem constants
#define NB   64          // batch*windows
#define NTOK 196         // tokens per window
#define NH   32          // heads
#define HD   4           // head dim
#define CE   128         // embed
#define NM   38416       // 196*196
#define ROWS 25088       // 2*64*196 (both branches stacked)

typedef __bf16 bf16x8 __attribute__((ext_vector_type(8)));
typedef float  f32x4  __attribute__((ext_vector_type(4)));

__device__ __forceinline__ float u2f(unsigned short u) {
    union { unsigned int i; float f; } z;
    z.i = ((unsigned int)u) << 16;
    return z.f;
}
__device__ __forceinline__ unsigned short f2u(float f) {
    union { float f; unsigned int i; } z; z.f = f;
    unsigned int x = z.i;
    return (unsigned short)((x + 0x7fffu + ((x >> 16) & 1u)) >> 16); // RNE
}

// ---------------------------------------------------------------------------
// Kernel 1: QKV GEMM via MFMA bf16.  out[r][j] = sum_c X[r][c] * W[j][c].
// Block tile 64(M) x 64(N), K=128 whole. 4 waves in 2x2; wave tile 32x32
// (2x2 frags of 16x16x32). LDS tiles [row][k] padded to 136 (2-way = free).
// ---------------------------------------------------------------------------
extern "C" __global__ __launch_bounds__(256) void qkv_gemm(
    const float* __restrict__ x1,
    const float* __restrict__ x2,
    const float* __restrict__ qkvw,
    float* __restrict__ Q, float* __restrict__ K, unsigned short* __restrict__ V)
{
    __shared__ alignas(16) unsigned short AT[64][136];
    __shared__ alignas(16) unsigned short BT[64][136];
    const int tid = threadIdx.x;
    const int r0 = blockIdx.x * 64;     // 0..391 -> rows
    const int j0 = blockIdx.y * 64;     // 0..5   -> cols of 384

    // stage A (rows of x1|x2), fp32 -> bf16
    for (int idx = tid; idx < 2048; idx += 256) {
        int row = idx >> 5, k0 = (idx & 31) << 2;
        int r = r0 + row;
        const float* xp = (r >= 12544) ? x2 : x1;
        int rem = r - ((r >= 12544) ? 12544 : 0);
        float4 v = *(const float4*)&xp[rem * 128 + k0];
        ushort4 u; u.x = f2u(v.x); u.y = f2u(v.y); u.z = f2u(v.z); u.w = f2u(v.w);
        *(ushort4*)&AT[row][k0] = u;
    }
    // stage B (rows of qkv_w = W[j][c], already the B^T layout we need)
    for (int idx = tid; idx < 2048; idx += 256) {
        int row = idx >> 5, k0 = (idx & 31) << 2;
        float4 v = *(const float4*)&qkvw[(j0 + row) * 128 + k0];
        ushort4 u; u.x = f2u(v.x); u.y = f2u(v.y); u.z = f2u(v.z); u.w = f2u(v.w);
        *(ushort4*)&BT[row][k0] = u;
    }
    __syncthreads();

    const int lane = tid & 63, w = tid >> 6;
    const int wm = (w >> 1) * 32, wn = (w & 1) * 32;
    const int quad = lane >> 4, tcol = lane & 15;

    f32x4 acc[2][2] = {};
#pragma unroll
    for (int ks = 0; ks < 4; ++ks) {
        int k0 = ks * 32 + quad * 8;
        bf16x8 a0 = *(const bf16x8*)&AT[wm + tcol][k0];
        bf16x8 a1 = *(const bf16x8*)&AT[wm + 16 + tcol][k0];
        bf16x8 b0 = *(const bf16x8*)&BT[wn + tcol][k0];
        bf16x8 b1 = *(const bf16x8*)&BT[wn + 16 + tcol][k0];
        acc[0][0] = __builtin_amdgcn_mfma_f32_16x16x32_bf16(a0, b0, acc[0][0], 0, 0, 0);
        acc[0][1] = __builtin_amdgcn_mfma_f32_16x16x32_bf16(a0, b1, acc[0][1], 0, 0, 0);
        acc[1][0] = __builtin_amdgcn_mfma_f32_16x16x32_bf16(a1, b0, acc[1][0], 0, 0, 0);
        acc[1][1] = __builtin_amdgcn_mfma_f32_16x16x32_bf16(a1, b1, acc[1][1], 0, 0, 0);
    }

#pragma unroll
    for (int mi = 0; mi < 2; ++mi) {
#pragma unroll
        for (int ni = 0; ni < 2; ++ni) {
            int jglob = j0 + wn + ni * 16 + tcol;
            int sel = jglob >> 7;            // 0=q 1=k 2=v (uniform per frag)
            int jj = jglob & 127;
            int h = jj >> 2, dd = jj & 3;
#pragma unroll
            for (int reg = 0; reg < 4; ++reg) {
                int r = r0 + wm + mi * 16 + quad * 4 + reg;
                int branch = (r >= 12544) ? 1 : 0;
                int rem = r - branch * 12544;
                int b = rem / 196;
                int n = rem - b * 196;
                float v = acc[mi][ni][reg];
                if (sel == 0) {
                    Q[((branch * 64 + b) * 32 + h) * 784 + n * 4 + dd] = v * 0.5f;
                } else if (sel == 1) {
                    K[((branch * 64 + b) * 32 + h) * 784 + n * 4 + dd] = v;
                } else {
                    V[(b * 64 + branch * 32 + h) * 784 + n * 4 + dd] = f2u(v);
                }
            }
        }
    }
}

// ---------------------------------------------------------------------------
// Kernel 2: bias gather, block per m, lane per n -> contiguous 2B stores.
// biasT[h][m*196+n] = rpb[rel_idx[n][m]][h]
// ---------------------------------------------------------------------------
extern "C" __global__ __launch_bounds__(256) void bias_gather(
    const int* __restrict__ rel_idx, const float* __restrict__ rpb,
    unsigned short* __restrict__ biasT)
{
    const int m = blockIdx.x;
    const int n = threadIdx.x;
    if (n >= 196) return;
    int idx = rel_idx[n * 196 + m];
    const float* row = rpb + idx * 32;
    unsigned short* o = biasT + m * 196 + n;
#pragma unroll
    for (int h = 0; h < 32; ++h)
        o[h * NM] = f2u(row[h]);
}

// ---------------------------------------------------------------------------
// Kernel 3: conv-gated value fusion + InstanceNorm + sigmoid(relu). (unchanged)
// ---------------------------------------------------------------------------
__device__ __forceinline__ float block_sum(float v, float* red, int tid) {
#pragma unroll
    for (int off = 32; off > 0; off >>= 1) v += __shfl_down(v, off);
    __syncthreads();
    if ((tid & 63) == 0) red[tid >> 6] = v;
    __syncthreads();
    return red[0] + red[1] + red[2] + red[3];
}

__device__ __forceinline__ float act_sig_relu(float x) {
    return x > 0.f ? __fdividef(1.f, 1.f + __expf(-x)) : 0.5f;
}

extern "C" __global__ __launch_bounds__(256) void fuse_kernel(
    const unsigned short* __restrict__ V,
    const float* __restrict__ fuse_w,
    const float* __restrict__ fuse_b,
    float* __restrict__ Vf)
{
    const int b = blockIdx.x, o0 = blockIdx.y * 2;
    const int tid = threadIdx.x;
    __shared__ float fws[2][64];
    __shared__ float red[4];
    if (tid < 128) fws[tid >> 6][tid & 63] = fuse_w[(o0 + (tid >> 6)) * 64 + (tid & 63)];
    __syncthreads();

    const unsigned short* Vb = V + b * 64 * 784;
    float a0[3] = {0.f, 0.f, 0.f}, a1[3] = {0.f, 0.f, 0.f};
    float t0 = 0.f, t1 = 0.f;
    const bool tail = tid < 16;
    for (int c = 0; c < 64; ++c) {
        float w0 = fws[0][c], w1 = fws[1][c];
        const unsigned short* Vc = Vb + c * 784;
#pragma unroll
        for (int k = 0; k < 3; ++k) {
            float x = u2f(Vc[tid + 256 * k]);
            a0[k] = fmaf(w0, x, a0[k]);
            a1[k] = fmaf(w1, x, a1[k]);
        }
        if (tail) {
            float x = u2f(Vc[tid + 768]);
            t0 = fmaf(w0, x, t0);
            t1 = fmaf(w1, x, t1);
        }
    }
    float fb0 = fuse_b[o0], fb1 = fuse_b[o0 + 1];
#pragma unroll
    for (int k = 0; k < 3; ++k) { a0[k] += fb0; a1[k] += fb1; }
    t0 += fb0; t1 += fb1;

    float s0 = a0[0] + a0[1] + a0[2] + (tail ? t0 : 0.f);
    float q0 = a0[0]*a0[0] + a0[1]*a0[1] + a0[2]*a0[2] + (tail ? t0*t0 : 0.f);
    float s1 = a1[0] + a1[1] + a1[2] + (tail ? t1 : 0.f);
    float q1 = a1[0]*a1[0] + a1[1]*a1[1] + a1[2]*a1[2] + (tail ? t1*t1 : 0.f);

    float S0 = block_sum(s0, red, tid);
    float Q0 = block_sum(q0, red, tid);
    float S1 = block_sum(s1, red, tid);
    float Q1 = block_sum(q1, red, tid);

    const float inv = 1.0f / 784.0f;
    float mu0 = S0 * inv, mu1 = S1 * inv;
    float rs0 = rsqrtf(Q0 * inv - mu0 * mu0 + 1e-5f);
    float rs1 = rsqrtf(Q1 * inv - mu1 * mu1 + 1e-5f);

    float* out0 = Vf + (b * 32 + o0) * 784;
    float* out1 = out0 + 784;
#pragma unroll
    for (int k = 0; k < 3; ++k) {
        int e = tid + 256 * k;
        out0[e] = act_sig_relu((a0[k] - mu0) * rs0);
        out1[e] = act_sig_relu((a1[k] - mu1) * rs1);
    }
    if (tail) {
        out0[tid + 768] = act_sig_relu((t0 - mu0) * rs0);
        out1[tid + 768] = act_sig_relu((t1 - mu1) * rs1);
    }
}

// ---------------------------------------------------------------------------
// Kernel 4: attention. (unchanged, known-correct)
// ---------------------------------------------------------------------------
extern "C" __global__ __launch_bounds__(256) void attn_kernel(
    const float* __restrict__ Q, const float* __restrict__ K,
    const float* __restrict__ Vf, const unsigned short* __restrict__ biasT,
    unsigned short* __restrict__ Ob)
{
    const int bh = blockIdx.x;
    const int b = bh >> 5, h = bh & 31;
    __shared__ float k1s[196][4];
    __shared__ float k2s[196][4];
    __shared__ float vfs[196][4];
    const int tid = threadIdx.x;
    const int base1 = (b * 32 + h) * 784;
    const int base2 = ((64 + b) * 32 + h) * 784;
    const int basev = (b * 32 + h) * 784;
    for (int idx = tid; idx < 784; idx += 256) {
        (&k1s[0][0])[idx] = K[base1 + idx];
        (&k2s[0][0])[idx] = K[base2 + idx];
        (&vfs[0][0])[idx] = Vf[basev + idx];
    }
    __syncthreads();

    const int n = tid;
    if (n < 196) {
        float4 q1 = *(const float4*)(Q + base1 + n * 4);
        float4 q2 = *(const float4*)(Q + base2 + n * 4);
        const unsigned short* bp = biasT + h * NM + n;
        float S = 0.f, o0 = 0.f, o1 = 0.f, o2 = 0.f, o3 = 0.f;
        for (int m = 0; m < 196; ++m) {
            float4 k1 = *(const float4*)&k1s[m][0];
            float4 k2 = *(const float4*)&k2s[m][0];
            float s = u2f(bp[m * 196]);
            s = fmaf(q1.x, k1.x, fmaf(q1.y, k1.y, fmaf(q1.z, k1.z, fmaf(q1.w, k1.w, s))));
            s = fmaf(q2.x, k2.x, fmaf(q2.y, k2.y, fmaf(q2.z, k2.z, fmaf(q2.w, k2.w, s))));
            float p = __expf(s);
            S += p;
            float4 vv = *(const float4*)&vfs[m][0];
            o0 = fmaf(p, vv.x, o0); o1 = fmaf(p, vv.y, o1);
            o2 = fmaf(p, vv.z, o2); o3 = fmaf(p, vv.w, o3);
        }
        float invS = __fdividef(1.f, S);
        unsigned short* op = Ob + (b * 196 + n) * 128 + h * 4;
        op[0] = f2u(o0 * invS); op[1] = f2u(o1 * invS);
        op[2] = f2u(o2 * invS); op[3] = f2u(o3 * invS);
    }
}

// ---------------------------------------------------------------------------
// Kernel 5: output projection via MFMA bf16. out = Ob @ projW^T + b (fp32 out)
// ---------------------------------------------------------------------------
extern "C" __global__ __launch_bounds__(256) void proj_kernel(
    const unsigned short* __restrict__ Ob, const float* __restrict__ projw,
    const float* __restrict__ projb, float* __restrict__ out)
{
    __shared__ alignas(16) unsigned short AT[64][136];
    __shared__ alignas(16) unsigned short BT[64][136];
    const int tid = threadIdx.x;
    const int r0 = blockIdx.x * 64;     // 0..195
    const int j0 = blockIdx.y * 64;     // 0..1

    // stage A: Ob rows (already bf16) -> 16B copies
    for (int idx = tid; idx < 1024; idx += 256) {
        int row = idx >> 4, k0 = (idx & 15) << 3;
        *(uint4*)&AT[row][k0] = *(const uint4*)&Ob[(r0 + row) * 128 + k0];
    }
    // stage B: projw rows fp32 -> bf16
    for (int idx = tid; idx < 2048; idx += 256) {
        int row = idx >> 5, k0 = (idx & 31) << 2;
        float4 v = *(const float4*)&projw[(j0 + row) * 128 + k0];
        ushort4 u; u.x = f2u(v.x); u.y = f2u(v.y); u.z = f2u(v.z); u.w = f2u(v.w);
        *(ushort4*)&BT[row][k0] = u;
    }
    __syncthreads();

    const int lane = tid & 63, w = tid >> 6;
    const int wm = (w >> 1) * 32, wn = (w & 1) * 32;
    const int quad = lane >> 4, tcol = lane & 15;

    f32x4 acc[2][2] = {};
#pragma unroll
    for (int ks = 0; ks < 4; ++ks) {
        int k0 = ks * 32 + quad * 8;
        bf16x8 a0 = *(const bf16x8*)&AT[wm + tcol][k0];
        bf16x8 a1 = *(const bf16x8*)&AT[wm + 16 + tcol][k0];
        bf16x8 b0 = *(const bf16x8*)&BT[wn + tcol][k0];
        bf16x8 b1 = *(const bf16x8*)&BT[wn + 16 + tcol][k0];
        acc[0][0] = __builtin_amdgcn_mfma_f32_16x16x32_bf16(a0, b0, acc[0][0], 0, 0, 0);
        acc[0][1] = __builtin_amdgcn_mfma_f32_16x16x32_bf16(a0, b1, acc[0][1], 0, 0, 0);
        acc[1][0] = __builtin_amdgcn_mfma_f32_16x16x32_bf16(a1, b0, acc[1][0], 0, 0, 0);
        acc[1][1] = __builtin_amdgcn_mfma_f32_16x16x32_bf16(a1, b1, acc[1][1], 0, 0, 0);
    }

#pragma unroll
    for (int mi = 0; mi < 2; ++mi) {
#pragma unroll
        for (int ni = 0; ni < 2; ++ni) {
            int j = j0 + wn + ni * 16 + tcol;
            float pb = projb[j];
#pragma unroll
            for (int reg = 0; reg < 4; ++reg) {
                int r = r0 + wm + mi * 16 + quad * 4 + reg;
                out[r * 128 + j] = acc[mi][ni][reg] + pb;
            }
        }
    }
}

// ---------------------------------------------------------------------------
extern "C" void kernel_launch(void* const* d_in, const int* in_sizes, int n_in,
                              void* d_out, int out_size, void* d_ws, size_t ws_size,
                              hipStream_t stream)
{
    const float* x1    = (const float*)d_in[0];
    const float* x2    = (const float*)d_in[1];
    const float* qkvw  = (const float*)d_in[2];
    const float* projw = (const float*)d_in[3];
    const float* projb = (const float*)d_in[4];
    const float* rpb   = (const float*)d_in[5];
    const float* fw    = (const float*)d_in[6];
    const float* fb    = (const float*)d_in[7];
    const int*   rel   = (const int*)d_in[8];
    float* out = (float*)d_out;

    char* w = (char*)d_ws;
    float* Q            = (float*)(w);                       // 12,845,056 B
    float* K            = (float*)(w + 12845056);            // 12,845,056 B
    unsigned short* V   = (unsigned short*)(w + 25690112);   //  6,422,528 B (bf16)
    float* Vf           = (float*)(w + 32112640);            //  6,422,528 B
    unsigned short* bT  = (unsigned short*)(w + 38535168);   //  2,458,624 B (bf16)
    unsigned short* Ob  = (unsigned short*)(w + 40993792);   //  3,211,264 B (bf16)

    qkv_gemm   <<<dim3(392, 6), dim3(256), 0, stream>>>(x1, x2, qkvw, Q, K, V);
    bias_gather<<<dim3(196),    dim3(256), 0, stream>>>(rel, rpb, bT);
    fuse_kernel<<<dim3(64, 16), dim3(256), 0, stream>>>(V, fw, fb, Vf);
    attn_kernel<<<dim3(2048),   dim3(256), 0, stream>>>(Q, K, Vf, bT, Ob);
    proj_kernel<<<dim3(196, 2), dim3(256), 0, stream>>>(Ob, projw, projb, out);
}